// Round 8
// baseline (3553.799 us; speedup 1.0000x reference)
//
#include <hip/hip_runtime.h>
#include <math.h>

#define B_ 8
#define N_ 4096
#define D_ 6
#define K_ 64
#define NS1_ 2048
#define NS2_ 512

typedef float v2f __attribute__((ext_vector_type(2)));

// ---------- helpers ----------

__device__ __forceinline__ float dist2_rn(const float* __restrict__ a, const float* __restrict__ q) {
    // exact np semantics: sequential sum of (a-b)^2, round-to-nearest each op, no fma
    float s = 0.f;
#pragma unroll
    for (int d = 0; d < 6; ++d) {
        float diff = __fsub_rn(a[d], q[d]);
        s = __fadd_rn(s, __fmul_rn(diff, diff));
    }
    return s;
}

__device__ __forceinline__ unsigned mapf(float x) {
    unsigned u = __float_as_uint(x);
    return (u & 0x80000000u) ? ~u : (u | 0x80000000u);
}
__device__ __forceinline__ float unmapf(unsigned u) {
    return __uint_as_float((u & 0x80000000u) ? (u & 0x7FFFFFFFu) : ~u);
}

// DPP moves; invalid lanes keep own value (identity for max/min reduces)
template <int CTRL>
__device__ __forceinline__ float dppf(float x) {
    int v = __float_as_int(x);
    return __int_as_float(__builtin_amdgcn_update_dpp(v, v, CTRL, 0xF, 0xF, false));
}
template <int CTRL>
__device__ __forceinline__ int dppi(int x) {
    return __builtin_amdgcn_update_dpp(x, x, CTRL, 0xF, 0xF, false);
}
template <int CTRL>
__device__ __forceinline__ double dppd(double k) {
    int lo = __double2loint(k), hi = __double2hiint(k);
    int nlo = __builtin_amdgcn_update_dpp(lo, lo, CTRL, 0xF, 0xF, false);
    int nhi = __builtin_amdgcn_update_dpp(hi, hi, CTRL, 0xF, 0xF, false);
    return __hiloint2double(nhi, nlo);
}

// ---------- FPS v8: value-only reduce + post-hoc index recovery ----------
// Update loop tracks only mind (vector pairs, contract(off) -> exact rn chain, pk-f32
// candidates) + lane max tree. Wave max via f32 DPP ladder -> readlane -> SGPR M.
// Index: mind==M is exact (max selects an element bitwise); cand = min gidx attaining M
// (min gidx == first occurrence in np scan order). Cross-wave: u64 key (M,~gidx) f64-fmax.

template <int NP, int NS, bool ZG>
__global__ __launch_bounds__(256, 1) void fps_kernel(const float* __restrict__ pos,
                                                     float* __restrict__ posq,
                                                     unsigned* __restrict__ g) {
#pragma clang fp contract(off)
    constexpr int NT = 256;
    constexpr int P = NP / NT;
    constexpr int HP = P / 2;
    int b = blockIdx.x, t = threadIdx.x;
    int lane = t & 63, w = t >> 6;
    const float* p = pos + (size_t)b * NP * 6;
    __shared__ float spos[NP * 6];   // row-major [j*6+d]
    __shared__ int sidx[NS];
    __shared__ double part[2][4];

    // stage into LDS, coalesced float4
    {
        const float4* src = (const float4*)p;
        float4* dst = (float4*)spos;
        for (int e = t; e < NP * 6 / 4; e += NT) dst[e] = src[e];
    }
    if (t == 0) sidx[0] = 0;
    __syncthreads();

    // this thread's points in vector pairs: pair j = points t+NT*(2j), t+NT*(2j+1)
    v2f px2[HP][6];
#pragma unroll
    for (int j = 0; j < HP; ++j)
#pragma unroll
        for (int d = 0; d < 6; ++d) {
            px2[j][d].x = spos[(t + NT * (2 * j)) * 6 + d];
            px2[j][d].y = spos[(t + NT * (2 * j + 1)) * 6 + d];
        }

    // first sample = point 0
    float cx[6];
#pragma unroll
    for (int d = 0; d < 6; ++d) cx[d] = spos[d];

    v2f mind2[HP];
    float lmax = -1.f;   // lane-local max of mind
#pragma unroll
    for (int j = 0; j < HP; ++j) {
        v2f d2 = {0.f, 0.f};
#pragma unroll
        for (int d = 0; d < 6; ++d) {
            v2f df = px2[j][d] - cx[d];
            d2 = d2 + df * df;
        }
        mind2[j] = d2;
        lmax = fmaxf(lmax, fmaxf(d2.x, d2.y));
    }

    for (int s = 1; s < NS; ++s) {
        // wave value reduce (f32 DPP ladder) -> lane 63 -> SGPR
        float m = lmax;
        m = fmaxf(m, dppf<0x111>(m));  // row_shr:1
        m = fmaxf(m, dppf<0x112>(m));  // row_shr:2
        m = fmaxf(m, dppf<0x114>(m));  // row_shr:4
        m = fmaxf(m, dppf<0x118>(m));  // row_shr:8
        m = fmaxf(m, dppf<0x142>(m));  // row_bcast:15
        m = fmaxf(m, dppf<0x143>(m));  // row_bcast:31
        float M = __uint_as_float((unsigned)__builtin_amdgcn_readlane((int)__float_as_uint(m), 63));

        // post-hoc index recovery: min gidx with mind == M (exact equality; gidx ascending == scan order)
        int cand = 0x7fffffff;
#pragma unroll
        for (int j = 0; j < HP; ++j) {
            cand = min(cand, (mind2[j].x == M) ? (t + NT * (2 * j)) : 0x7fffffff);
            cand = min(cand, (mind2[j].y == M) ? (t + NT * (2 * j + 1)) : 0x7fffffff);
        }
        // wave index min reduce
        cand = min(cand, dppi<0x111>(cand));
        cand = min(cand, dppi<0x112>(cand));
        cand = min(cand, dppi<0x114>(cand));
        cand = min(cand, dppi<0x118>(cand));
        cand = min(cand, dppi<0x142>(cand));
        cand = min(cand, dppi<0x143>(cand));
        int gw = __builtin_amdgcn_readlane(cand, 63);

        // cross-wave combine via u64 key (M bits, ~gidx), f64-fmax 2-level DPP
        if (lane == 0) part[s & 1][w] = __hiloint2double((int)__float_as_uint(M), (int)(unsigned)(~gw));
        __syncthreads();
        double kk = part[s & 1][lane & 3];
        kk = fmax(kk, dppd<0x111>(kk));
        kk = fmax(kk, dppd<0x112>(kk));   // lane 3 = max of partials 0..3
        int nx = ~__builtin_amdgcn_readlane(__double2loint(kk), 3);
        if (t == 0) sidx[s] = nx;  // off critical path; consumed only at the end

        // broadcast-read new center coords (nx uniform)
        const float2* sv2 = (const float2*)spos;
        float2 ca = sv2[nx * 3], cb = sv2[nx * 3 + 1], cc = sv2[nx * 3 + 2];
        cx[0] = ca.x; cx[1] = ca.y; cx[2] = cb.x; cx[3] = cb.y; cx[4] = cc.x; cx[5] = cc.y;

        // fused update + lane max (no index tracking in the hot loop)
        lmax = -1.f;
#pragma unroll
        for (int j = 0; j < HP; ++j) {
            v2f d2 = {0.f, 0.f};
#pragma unroll
            for (int d = 0; d < 6; ++d) {
                v2f df = px2[j][d] - cx[d];
                d2 = d2 + df * df;
            }
            float mx = fminf(mind2[j].x, d2.x);
            float my = fminf(mind2[j].y, d2.y);
            mind2[j].x = mx;
            mind2[j].y = my;
            lmax = fmaxf(lmax, fmaxf(mx, my));
        }
    }
    __syncthreads();
    // write posq once, from LDS
    for (int s2 = t; s2 < NS; s2 += NT) {
        int nx = sidx[s2];
#pragma unroll
        for (int d = 0; d < 6; ++d) posq[((size_t)b * NS + s2) * 6 + d] = spos[nx * 6 + d];
    }
    if (ZG) {  // fold init_g into fps2: zero the global-max buffer (consumed by mlp3 later)
        for (int e = t; e < 1024; e += NT) g[b * 1024 + e] = 0u;
    }
}

// ---------- ball query: one thread per query, block=64, interleaved LDS top-K ----------

__global__ __launch_bounds__(64) void ball_kernel(const float* __restrict__ pos, const float* __restrict__ posq,
                                                  int* __restrict__ nbr, int* __restrict__ cnt,
                                                  int N, int nq, float r2) {
    __shared__ float sd[K_ * 64];
    __shared__ int si[K_ * 64];
    int tid = threadIdx.x;
    int qid = blockIdx.x * 64 + tid;
    int b = qid / nq;
    const float* p = pos + (size_t)b * N * 6;
    float q[6];
#pragma unroll
    for (int d = 0; d < 6; ++d) q[d] = posq[(size_t)qid * 6 + d];

    int n = 0;
    for (int j = 0; j < N; ++j) {
        float d2 = dist2_rn(p + (size_t)j * 6, q);
        if (d2 <= r2) {
            if (n < K_) {
                int i = n++;
                while (i > 0 && sd[(i - 1) * 64 + tid] > d2) {
                    sd[i * 64 + tid] = sd[(i - 1) * 64 + tid];
                    si[i * 64 + tid] = si[(i - 1) * 64 + tid];
                    --i;
                }
                sd[i * 64 + tid] = d2;
                si[i * 64 + tid] = j;
            } else if (d2 < sd[(K_ - 1) * 64 + tid]) {
                int i = K_ - 1;
                while (i > 0 && sd[(i - 1) * 64 + tid] > d2) {
                    sd[i * 64 + tid] = sd[(i - 1) * 64 + tid];
                    si[i * 64 + tid] = si[(i - 1) * 64 + tid];
                    --i;
                }
                sd[i * 64 + tid] = d2;
                si[i * 64 + tid] = j;
            }
        }
    }
    cnt[qid] = n;
    for (int i = 0; i < n; ++i) nbr[(size_t)qid * K_ + i] = si[i * 64 + tid];
}

// ---------- SA1 conv: one wave per query; MLP 6->64->64->128, max over valid neighbors ----------

__global__ __launch_bounds__(256) void sa1_conv(const float* __restrict__ pos, const float* __restrict__ posq,
                                                const int* __restrict__ nbr, const int* __restrict__ cnt,
                                                const float* __restrict__ W1, const float* __restrict__ B1,
                                                const float* __restrict__ W2, const float* __restrict__ B2,
                                                const float* __restrict__ W3, const float* __restrict__ B3,
                                                float* __restrict__ out, int N, int nq) {
    int lane = threadIdx.x & 63;
    int w = threadIdx.x >> 6;
    int qid = blockIdx.x * 4 + w;
    int b = qid / nq;
    const float* p = pos + (size_t)b * N * 6;
    float q[6];
#pragma unroll
    for (int d = 0; d < 6; ++d) q[d] = posq[(size_t)qid * 6 + d];
    int c = cnt[qid];
    float m0 = -INFINITY, m1 = -INFINITY;

    for (int n = 0; n < c; ++n) {
        int j = nbr[(size_t)qid * K_ + n];
        float rel[6];
#pragma unroll
        for (int d = 0; d < 6; ++d) rel[d] = p[(size_t)j * 6 + d] - q[d];
        float a = B1[lane];
#pragma unroll
        for (int d = 0; d < 6; ++d) a = fmaf(W1[d * 64 + lane], rel[d], a);
        float h1 = fmaxf(a, 0.f);
        float a2 = B2[lane];
        for (int k = 0; k < 64; ++k) {
            float v = __shfl(h1, k, 64);
            a2 = fmaf(W2[k * 64 + lane], v, a2);
        }
        float h2 = fmaxf(a2, 0.f);
        float o0 = B3[lane], o1 = B3[64 + lane];
        for (int k = 0; k < 64; ++k) {
            float v = __shfl(h2, k, 64);
            o0 = fmaf(W3[k * 128 + lane], v, o0);
            o1 = fmaf(W3[k * 128 + 64 + lane], v, o1);
        }
        m0 = fmaxf(m0, o0);
        m1 = fmaxf(m1, o1);
    }
    out[(size_t)qid * 128 + lane] = m0;
    out[(size_t)qid * 128 + 64 + lane] = m1;
}

// ---------- SA2 conv: one wave per query; feat=[x1(128), rel(6)] -> 128 -> 128 -> 256 ----------

__global__ __launch_bounds__(256) void sa2_conv(const float* __restrict__ pos1, const float* __restrict__ posq,
                                                const int* __restrict__ nbr, const int* __restrict__ cnt,
                                                const float* __restrict__ x1,
                                                const float* __restrict__ W1, const float* __restrict__ B1,
                                                const float* __restrict__ W2, const float* __restrict__ B2,
                                                const float* __restrict__ W3, const float* __restrict__ B3,
                                                float* __restrict__ out) {
    int lane = threadIdx.x & 63;
    int w = threadIdx.x >> 6;
    int qid = blockIdx.x * 4 + w;
    int b = qid / NS2_;
    float q[6];
#pragma unroll
    for (int d = 0; d < 6; ++d) q[d] = posq[(size_t)qid * 6 + d];
    int c = cnt[qid];
    float m0 = -INFINITY, m1 = -INFINITY, m2 = -INFINITY, m3 = -INFINITY;

    for (int n = 0; n < c; ++n) {
        int j = nbr[(size_t)qid * K_ + n];
        size_t row = (size_t)b * NS1_ + j;
        const float* xs = x1 + row * 128;
        float rel[6];
#pragma unroll
        for (int d = 0; d < 6; ++d) rel[d] = pos1[row * 6 + d] - q[d];
        float a0 = B1[lane], a1 = B1[64 + lane];
        for (int k = 0; k < 128; ++k) {
            float v = xs[k];
            a0 = fmaf(W1[k * 128 + lane], v, a0);
            a1 = fmaf(W1[k * 128 + 64 + lane], v, a1);
        }
#pragma unroll
        for (int d = 0; d < 6; ++d) {
            float v = rel[d];
            a0 = fmaf(W1[(128 + d) * 128 + lane], v, a0);
            a1 = fmaf(W1[(128 + d) * 128 + 64 + lane], v, a1);
        }
        float h1a = fmaxf(a0, 0.f), h1b = fmaxf(a1, 0.f);
        float c0 = B2[lane], c1 = B2[64 + lane];
        for (int k = 0; k < 64; ++k) {
            float v = __shfl(h1a, k, 64);
            c0 = fmaf(W2[k * 128 + lane], v, c0);
            c1 = fmaf(W2[k * 128 + 64 + lane], v, c1);
        }
        for (int k = 0; k < 64; ++k) {
            float v = __shfl(h1b, k, 64);
            c0 = fmaf(W2[(64 + k) * 128 + lane], v, c0);
            c1 = fmaf(W2[(64 + k) * 128 + 64 + lane], v, c1);
        }
        float h2a = fmaxf(c0, 0.f), h2b = fmaxf(c1, 0.f);
        float e0 = B3[lane], e1 = B3[64 + lane], e2 = B3[128 + lane], e3 = B3[192 + lane];
        for (int k = 0; k < 64; ++k) {
            float v = __shfl(h2a, k, 64);
            e0 = fmaf(W3[k * 256 + lane], v, e0);
            e1 = fmaf(W3[k * 256 + 64 + lane], v, e1);
            e2 = fmaf(W3[k * 256 + 128 + lane], v, e2);
            e3 = fmaf(W3[k * 256 + 192 + lane], v, e3);
        }
        for (int k = 0; k < 64; ++k) {
            float v = __shfl(h2b, k, 64);
            e0 = fmaf(W3[(64 + k) * 256 + lane], v, e0);
            e1 = fmaf(W3[(64 + k) * 256 + 64 + lane], v, e1);
            e2 = fmaf(W3[(64 + k) * 256 + 128 + lane], v, e2);
            e3 = fmaf(W3[(64 + k) * 256 + 192 + lane], v, e3);
        }
        m0 = fmaxf(m0, e0);
        m1 = fmaxf(m1, e1);
        m2 = fmaxf(m2, e2);
        m3 = fmaxf(m3, e3);
    }
    out[(size_t)qid * 256 + lane] = m0;
    out[(size_t)qid * 256 + 64 + lane] = m1;
    out[(size_t)qid * 256 + 128 + lane] = m2;
    out[(size_t)qid * 256 + 192 + lane] = m3;
}

// ---------- MLP3 v2: wave = 4 queries register-blocked; weight float4 reused across queries ----------

__global__ __launch_bounds__(256, 1) void mlp3_kernel(const float* __restrict__ x2, const float* __restrict__ pos2,
                                                      const float* __restrict__ W0, const float* __restrict__ B0,
                                                      const float* __restrict__ W1, const float* __restrict__ B1,
                                                      const float* __restrict__ W2, const float* __restrict__ B2,
                                                      unsigned* __restrict__ g) {
    int lane = threadIdx.x & 63;
    int w = threadIdx.x >> 6;
    int qid0 = blockIdx.x * 16 + w * 4;  // 4 queries per wave, 16 per block
    int b = qid0 >> 9;                   // 512 queries per cloud

    float xr[4][4];
#pragma unroll
    for (int q = 0; q < 4; ++q)
#pragma unroll
        for (int j = 0; j < 4; ++j) xr[q][j] = x2[(size_t)(qid0 + q) * 256 + j * 64 + lane];

    // ---- L1: 262 -> 256, out channel = lane*4+u ----
    float a[4][4];
    {
        float4 bv = *(const float4*)&B0[lane * 4];
#pragma unroll
        for (int q = 0; q < 4; ++q) { a[q][0] = bv.x; a[q][1] = bv.y; a[q][2] = bv.z; a[q][3] = bv.w; }
    }
#pragma unroll
    for (int j = 0; j < 4; ++j) {
        for (int k2 = 0; k2 < 64; ++k2) {
            int k = j * 64 + k2;
            float4 wv = *(const float4*)&W0[(size_t)k * 256 + lane * 4];
#pragma unroll
            for (int q = 0; q < 4; ++q) {
                float v = __shfl(xr[q][j], k2, 64);
                a[q][0] = fmaf(wv.x, v, a[q][0]);
                a[q][1] = fmaf(wv.y, v, a[q][1]);
                a[q][2] = fmaf(wv.z, v, a[q][2]);
                a[q][3] = fmaf(wv.w, v, a[q][3]);
            }
        }
    }
#pragma unroll
    for (int d = 0; d < 6; ++d) {
        float4 wv = *(const float4*)&W0[(size_t)(256 + d) * 256 + lane * 4];
#pragma unroll
        for (int q = 0; q < 4; ++q) {
            float v = pos2[(size_t)(qid0 + q) * 6 + d];
            a[q][0] = fmaf(wv.x, v, a[q][0]);
            a[q][1] = fmaf(wv.y, v, a[q][1]);
            a[q][2] = fmaf(wv.z, v, a[q][2]);
            a[q][3] = fmaf(wv.w, v, a[q][3]);
        }
    }
    float h1[4][4];
#pragma unroll
    for (int q = 0; q < 4; ++q)
#pragma unroll
        for (int u = 0; u < 4; ++u) h1[q][u] = fmaxf(a[q][u], 0.f);

    // ---- L2: 256 -> 512, out channel = lane*8+u ----
    float c[4][8];
    {
        float4 b0 = *(const float4*)&B1[lane * 8];
        float4 b1 = *(const float4*)&B1[lane * 8 + 4];
#pragma unroll
        for (int q = 0; q < 4; ++q) {
            c[q][0] = b0.x; c[q][1] = b0.y; c[q][2] = b0.z; c[q][3] = b0.w;
            c[q][4] = b1.x; c[q][5] = b1.y; c[q][6] = b1.z; c[q][7] = b1.w;
        }
    }
    for (int l = 0; l < 64; ++l) {
#pragma unroll
        for (int r = 0; r < 4; ++r) {
            int k = l * 4 + r;
            float4 w0 = *(const float4*)&W1[(size_t)k * 512 + lane * 8];
            float4 w1 = *(const float4*)&W1[(size_t)k * 512 + lane * 8 + 4];
#pragma unroll
            for (int q = 0; q < 4; ++q) {
                float v = __shfl(h1[q][r], l, 64);
                c[q][0] = fmaf(w0.x, v, c[q][0]);
                c[q][1] = fmaf(w0.y, v, c[q][1]);
                c[q][2] = fmaf(w0.z, v, c[q][2]);
                c[q][3] = fmaf(w0.w, v, c[q][3]);
                c[q][4] = fmaf(w1.x, v, c[q][4]);
                c[q][5] = fmaf(w1.y, v, c[q][5]);
                c[q][6] = fmaf(w1.z, v, c[q][6]);
                c[q][7] = fmaf(w1.w, v, c[q][7]);
            }
        }
    }
    float h2[4][8];
#pragma unroll
    for (int q = 0; q < 4; ++q)
#pragma unroll
        for (int u = 0; u < 8; ++u) h2[q][u] = fmaxf(c[q][u], 0.f);

    // ---- L3: 512 -> 1024, out channel = lane*16+u ----
    float e[4][16];
#pragma unroll
    for (int jj = 0; jj < 4; ++jj) {
        float4 bv = *(const float4*)&B2[lane * 16 + jj * 4];
#pragma unroll
        for (int q = 0; q < 4; ++q) {
            e[q][jj * 4 + 0] = bv.x; e[q][jj * 4 + 1] = bv.y;
            e[q][jj * 4 + 2] = bv.z; e[q][jj * 4 + 3] = bv.w;
        }
    }
    for (int l = 0; l < 64; ++l) {
#pragma unroll
        for (int r = 0; r < 8; ++r) {
            int k = l * 8 + r;
            const float* wp = &W2[(size_t)k * 1024 + lane * 16];
            float4 w0 = *(const float4*)&wp[0];
            float4 w1 = *(const float4*)&wp[4];
            float4 w2 = *(const float4*)&wp[8];
            float4 w3 = *(const float4*)&wp[12];
#pragma unroll
            for (int q = 0; q < 4; ++q) {
                float v = __shfl(h2[q][r], l, 64);
                e[q][0]  = fmaf(w0.x, v, e[q][0]);
                e[q][1]  = fmaf(w0.y, v, e[q][1]);
                e[q][2]  = fmaf(w0.z, v, e[q][2]);
                e[q][3]  = fmaf(w0.w, v, e[q][3]);
                e[q][4]  = fmaf(w1.x, v, e[q][4]);
                e[q][5]  = fmaf(w1.y, v, e[q][5]);
                e[q][6]  = fmaf(w1.z, v, e[q][6]);
                e[q][7]  = fmaf(w1.w, v, e[q][7]);
                e[q][8]  = fmaf(w2.x, v, e[q][8]);
                e[q][9]  = fmaf(w2.y, v, e[q][9]);
                e[q][10] = fmaf(w2.z, v, e[q][10]);
                e[q][11] = fmaf(w2.w, v, e[q][11]);
                e[q][12] = fmaf(w3.x, v, e[q][12]);
                e[q][13] = fmaf(w3.y, v, e[q][13]);
                e[q][14] = fmaf(w3.z, v, e[q][14]);
                e[q][15] = fmaf(w3.w, v, e[q][15]);
            }
        }
    }
#pragma unroll
    for (int u = 0; u < 16; ++u) {
        float m = fmaxf(fmaxf(e[0][u], e[1][u]), fmaxf(e[2][u], e[3][u]));
        atomicMax(&g[b * 1024 + lane * 16 + u], mapf(m));
    }
}

// ---------- MLP4: 1024 -> 512 (relu) -> 512; one block per b ----------

__global__ __launch_bounds__(512) void mlp4_kernel(const unsigned* __restrict__ g,
                                                   const float* __restrict__ W0, const float* __restrict__ B0,
                                                   const float* __restrict__ W1, const float* __restrict__ B1,
                                                   float* __restrict__ out) {
    int b = blockIdx.x;
    int c = threadIdx.x;
    __shared__ float h[512];
    float a = B0[c];
    for (int k = 0; k < 1024; ++k) {
        float v = unmapf(g[b * 1024 + k]);
        a = fmaf(v, W0[k * 512 + c], a);
    }
    h[c] = fmaxf(a, 0.f);
    __syncthreads();
    float o = B1[c];
    for (int k = 0; k < 512; ++k) o = fmaf(h[k], W1[k * 512 + c], o);
    out[(size_t)b * 512 + c] = o;
}

// ---------- launch ----------

extern "C" void kernel_launch(void* const* d_in, const int* in_sizes, int n_in,
                              void* d_out, int out_size, void* d_ws, size_t ws_size,
                              hipStream_t stream) {
    const float* pos = (const float*)d_in[0];  // [B*N, 6]
    const float* w1_0 = (const float*)d_in[3];
    const float* b1_0 = (const float*)d_in[4];
    const float* w1_1 = (const float*)d_in[5];
    const float* b1_1 = (const float*)d_in[6];
    const float* w1_2 = (const float*)d_in[7];
    const float* b1_2 = (const float*)d_in[8];
    const float* w2_0 = (const float*)d_in[9];
    const float* b2_0 = (const float*)d_in[10];
    const float* w2_1 = (const float*)d_in[11];
    const float* b2_1 = (const float*)d_in[12];
    const float* w2_2 = (const float*)d_in[13];
    const float* b2_2 = (const float*)d_in[14];
    const float* w3_0 = (const float*)d_in[15];
    const float* b3_0 = (const float*)d_in[16];
    const float* w3_1 = (const float*)d_in[17];
    const float* b3_1 = (const float*)d_in[18];
    const float* w3_2 = (const float*)d_in[19];
    const float* b3_2 = (const float*)d_in[20];
    const float* w4_0 = (const float*)d_in[21];
    const float* b4_0 = (const float*)d_in[22];
    const float* w4_1 = (const float*)d_in[23];
    const float* b4_1 = (const float*)d_in[24];
    float* out = (float*)d_out;

    char* ws = (char*)d_ws;
    size_t off = 0;
    float* pos1 = (float*)(ws + off);  off += (size_t)B_ * NS1_ * 6 * 4;
    int* nbr1 = (int*)(ws + off);      off += (size_t)B_ * NS1_ * K_ * 4;
    int* cnt1 = (int*)(ws + off);      off += (size_t)B_ * NS1_ * 4;
    float* x1 = (float*)(ws + off);    off += (size_t)B_ * NS1_ * 128 * 4;
    float* pos2 = (float*)(ws + off);  off += (size_t)B_ * NS2_ * 6 * 4;
    int* nbr2 = (int*)(ws + off);      off += (size_t)B_ * NS2_ * K_ * 4;
    int* cnt2 = (int*)(ws + off);      off += (size_t)B_ * NS2_ * 4;
    float* x2 = (float*)(ws + off);    off += (size_t)B_ * NS2_ * 256 * 4;
    unsigned* g = (unsigned*)(ws + off); off += (size_t)B_ * 1024 * 4;

    const float r2_1 = (float)(0.2 * 0.2);
    const float r2_2 = (float)(0.4 * 0.4);

    // SA1
    fps_kernel<N_, NS1_, false><<<B_, 256, 0, stream>>>(pos, pos1, nullptr);
    ball_kernel<<<(B_ * NS1_) / 64, 64, 0, stream>>>(pos, pos1, nbr1, cnt1, N_, NS1_, r2_1);
    sa1_conv<<<(B_ * NS1_) / 4, 256, 0, stream>>>(pos, pos1, nbr1, cnt1,
                                                  w1_0, b1_0, w1_1, b1_1, w1_2, b1_2, x1, N_, NS1_);
    // SA2 (fps2 also zeroes g for mlp3)
    fps_kernel<NS1_, NS2_, true><<<B_, 256, 0, stream>>>(pos1, pos2, g);
    ball_kernel<<<(B_ * NS2_) / 64, 64, 0, stream>>>(pos1, pos2, nbr2, cnt2, NS1_, NS2_, r2_2);
    sa2_conv<<<(B_ * NS2_) / 4, 256, 0, stream>>>(pos1, pos2, nbr2, cnt2, x1,
                                                  w2_0, b2_0, w2_1, b2_1, w2_2, b2_2, x2);
    // MLP3 + global max
    mlp3_kernel<<<(B_ * NS2_) / 16, 256, 0, stream>>>(x2, pos2, w3_0, b3_0, w3_1, b3_1, w3_2, b3_2, g);
    // MLP4
    mlp4_kernel<<<B_, 512, 0, stream>>>(g, w4_0, b4_0, w4_1, b4_1, out);
}

// Round 9
// 3153.840 us; speedup vs baseline: 1.1268x; 1.1268x over previous
//
#include <hip/hip_runtime.h>
#include <math.h>

#define B_ 8
#define N_ 4096
#define D_ 6
#define K_ 64
#define NS1_ 2048
#define NS2_ 512

typedef float v2f __attribute__((ext_vector_type(2)));

// ---------- helpers ----------

__device__ __forceinline__ float dist2_rn(const float* __restrict__ a, const float* __restrict__ q) {
    // exact np semantics: sequential sum of (a-b)^2, round-to-nearest each op, no fma
    float s = 0.f;
#pragma unroll
    for (int d = 0; d < 6; ++d) {
        float diff = __fsub_rn(a[d], q[d]);
        s = __fadd_rn(s, __fmul_rn(diff, diff));
    }
    return s;
}

__device__ __forceinline__ unsigned mapf(float x) {
    unsigned u = __float_as_uint(x);
    return (u & 0x80000000u) ? ~u : (u | 0x80000000u);
}
__device__ __forceinline__ float unmapf(unsigned u) {
    return __uint_as_float((u & 0x80000000u) ? (u & 0x7FFFFFFFu) : ~u);
}

// DPP move on a f64 key (two 32-bit DPPs); invalid lanes keep own value (identity for max).
// Keys are non-negative doubles bitwise == (d2_fp32_bits<<32 | ~idx): u64 order == f64 order.
template <int CTRL>
__device__ __forceinline__ double dppd(double k) {
    int lo = __double2loint(k), hi = __double2hiint(k);
    int nlo = __builtin_amdgcn_update_dpp(lo, lo, CTRL, 0xF, 0xF, false);
    int nhi = __builtin_amdgcn_update_dpp(hi, hi, CTRL, 0xF, 0xF, false);
    return __hiloint2double(nhi, nlo);
}

// ---------- FPS v9: v7 reduce (single f64-fmax DPP ladder) + vector-IR update (v_pk_f32) ----------
// Update uses whole-vector v2f ops (<2 x float> IR -> v_pk_add/mul_f32); contract(off) keeps the
// exact rn chain (pk ops are the same IEEE ALU). min + argmax tracking stay scalar on components
// (no pk min on gfx950). Selection bit-identical to np: strict > on ascending gidx = first occurrence.

template <int NP, int NS, bool ZG>
__global__ __launch_bounds__(256, 1) void fps_kernel(const float* __restrict__ pos,
                                                     float* __restrict__ posq,
                                                     unsigned* __restrict__ g) {
#pragma clang fp contract(off)
    constexpr int NT = 256;
    constexpr int P = NP / NT;
    constexpr int HP = P / 2;
    int b = blockIdx.x, t = threadIdx.x;
    int lane = t & 63, w = t >> 6;
    const float* p = pos + (size_t)b * NP * 6;
    __shared__ float spos[NP * 6];   // row-major [j*6+d]
    __shared__ int sidx[NS];
    __shared__ double part[2][4];

    // stage into LDS, coalesced float4
    {
        const float4* src = (const float4*)p;
        float4* dst = (float4*)spos;
        for (int e = t; e < NP * 6 / 4; e += NT) dst[e] = src[e];
    }
    if (t == 0) sidx[0] = 0;
    __syncthreads();

    // this thread's points in vector pairs: pair j = points t+NT*(2j), t+NT*(2j+1)
    v2f px2[HP][6];
#pragma unroll
    for (int j = 0; j < HP; ++j)
#pragma unroll
        for (int d = 0; d < 6; ++d) {
            px2[j][d].x = spos[(t + NT * (2 * j)) * 6 + d];
            px2[j][d].y = spos[(t + NT * (2 * j + 1)) * 6 + d];
        }

    // first sample = point 0
    float cx[6];
#pragma unroll
    for (int d = 0; d < 6; ++d) cx[d] = spos[d];

    v2f mind2[HP];
    float runv = -1.f;
    int runj = 0;
#pragma unroll
    for (int j = 0; j < HP; ++j) {
        v2f d2 = {0.f, 0.f};
#pragma unroll
        for (int d = 0; d < 6; ++d) {
            v2f df = px2[j][d] - cx[d];
            d2 = d2 + df * df;
        }
        mind2[j] = d2;
        if (d2.x > runv) { runv = d2.x; runj = t + NT * (2 * j); }      // ascending gidx:
        if (d2.y > runv) { runv = d2.y; runj = t + NT * (2 * j + 1); }  // strict > keeps lowest
    }

    for (int s = 1; s < NS; ++s) {
        // wave-level argmax reduce via f64-fmax DPP ladder on packed key (v7-proven)
        double key = __hiloint2double((int)__float_as_uint(runv), (int)(unsigned)(~runj));
        key = fmax(key, dppd<0x111>(key));  // row_shr:1
        key = fmax(key, dppd<0x112>(key));  // row_shr:2
        key = fmax(key, dppd<0x114>(key));  // row_shr:4
        key = fmax(key, dppd<0x118>(key));  // row_shr:8
        key = fmax(key, dppd<0x142>(key));  // row_bcast:15
        key = fmax(key, dppd<0x143>(key));  // row_bcast:31 -> lane 63 = wave max
        if (lane == 63) part[s & 1][w] = key;
        __syncthreads();
        // every wave redundantly reduces the 4 partials (2 DPP levels, lanes 0..3)
        double kk = part[s & 1][lane & 3];
        kk = fmax(kk, dppd<0x111>(kk));
        kk = fmax(kk, dppd<0x112>(kk));   // lane 3 = max of partials 0..3
        int nx = ~__builtin_amdgcn_readlane(__double2loint(kk), 3);
        if (t == 0) sidx[s] = nx;  // off critical path; consumed only at the end

        // broadcast-read new center coords (nx uniform)
        const float2* sv2 = (const float2*)spos;
        float2 ca = sv2[nx * 3], cb = sv2[nx * 3 + 1], cc = sv2[nx * 3 + 2];
        cx[0] = ca.x; cx[1] = ca.y; cx[2] = cb.x; cx[3] = cb.y; cx[4] = cc.x; cx[5] = cc.y;

        // fused update (vector, packs to v_pk_*) + scalar min/argmax on components
        runv = -1.f;
        runj = 0;
#pragma unroll
        for (int j = 0; j < HP; ++j) {
            v2f d2 = {0.f, 0.f};
#pragma unroll
            for (int d = 0; d < 6; ++d) {
                v2f df = px2[j][d] - cx[d];
                d2 = d2 + df * df;
            }
            float mx = fminf(mind2[j].x, d2.x);
            float my = fminf(mind2[j].y, d2.y);
            mind2[j].x = mx;
            mind2[j].y = my;
            if (mx > runv) { runv = mx; runj = t + NT * (2 * j); }
            if (my > runv) { runv = my; runj = t + NT * (2 * j + 1); }
        }
    }
    __syncthreads();
    // write posq once, from LDS
    for (int s2 = t; s2 < NS; s2 += NT) {
        int nx = sidx[s2];
#pragma unroll
        for (int d = 0; d < 6; ++d) posq[((size_t)b * NS + s2) * 6 + d] = spos[nx * 6 + d];
    }
    if (ZG) {  // fold init_g into fps2: zero the global-max buffer (consumed by mlp3 later)
        for (int e = t; e < 1024; e += NT) g[b * 1024 + e] = 0u;
    }
}

// ---------- ball query: one thread per query, block=64, interleaved LDS top-K ----------
// unroll 4 pipelines the global loads; thr register caches sd[K-1] (same semantics:
// insert iff d2<=r2 && (n<K || d2<thr); ascending-j stable insertion unchanged).

__global__ __launch_bounds__(64) void ball_kernel(const float* __restrict__ pos, const float* __restrict__ posq,
                                                  int* __restrict__ nbr, int* __restrict__ cnt,
                                                  int N, int nq, float r2) {
    __shared__ float sd[K_ * 64];
    __shared__ int si[K_ * 64];
    int tid = threadIdx.x;
    int qid = blockIdx.x * 64 + tid;
    int b = qid / nq;
    const float* p = pos + (size_t)b * N * 6;
    float q[6];
#pragma unroll
    for (int d = 0; d < 6; ++d) q[d] = posq[(size_t)qid * 6 + d];

    int n = 0;
    float thr = INFINITY;
#pragma unroll 4
    for (int j = 0; j < N; ++j) {
        float d2 = dist2_rn(p + (size_t)j * 6, q);
        if (d2 <= r2 && (n < K_ || d2 < thr)) {
            int i = (n < K_) ? n : (K_ - 1);
            if (n < K_) ++n;
            while (i > 0 && sd[(i - 1) * 64 + tid] > d2) {
                sd[i * 64 + tid] = sd[(i - 1) * 64 + tid];
                si[i * 64 + tid] = si[(i - 1) * 64 + tid];
                --i;
            }
            sd[i * 64 + tid] = d2;
            si[i * 64 + tid] = j;
            if (n == K_) thr = sd[(K_ - 1) * 64 + tid];
        }
    }
    cnt[qid] = n;
    for (int i = 0; i < n; ++i) nbr[(size_t)qid * K_ + i] = si[i * 64 + tid];
}

// ---------- SA1 conv: one wave per query; MLP 6->64->64->128, max over valid neighbors ----------

__global__ __launch_bounds__(256) void sa1_conv(const float* __restrict__ pos, const float* __restrict__ posq,
                                                const int* __restrict__ nbr, const int* __restrict__ cnt,
                                                const float* __restrict__ W1, const float* __restrict__ B1,
                                                const float* __restrict__ W2, const float* __restrict__ B2,
                                                const float* __restrict__ W3, const float* __restrict__ B3,
                                                float* __restrict__ out, int N, int nq) {
    int lane = threadIdx.x & 63;
    int w = threadIdx.x >> 6;
    int qid = blockIdx.x * 4 + w;
    int b = qid / nq;
    const float* p = pos + (size_t)b * N * 6;
    float q[6];
#pragma unroll
    for (int d = 0; d < 6; ++d) q[d] = posq[(size_t)qid * 6 + d];
    int c = cnt[qid];
    float m0 = -INFINITY, m1 = -INFINITY;

    for (int n = 0; n < c; ++n) {
        int j = nbr[(size_t)qid * K_ + n];
        float rel[6];
#pragma unroll
        for (int d = 0; d < 6; ++d) rel[d] = p[(size_t)j * 6 + d] - q[d];
        float a = B1[lane];
#pragma unroll
        for (int d = 0; d < 6; ++d) a = fmaf(W1[d * 64 + lane], rel[d], a);
        float h1 = fmaxf(a, 0.f);
        float a2 = B2[lane];
        for (int k = 0; k < 64; ++k) {
            float v = __shfl(h1, k, 64);
            a2 = fmaf(W2[k * 64 + lane], v, a2);
        }
        float h2 = fmaxf(a2, 0.f);
        float o0 = B3[lane], o1 = B3[64 + lane];
        for (int k = 0; k < 64; ++k) {
            float v = __shfl(h2, k, 64);
            o0 = fmaf(W3[k * 128 + lane], v, o0);
            o1 = fmaf(W3[k * 128 + 64 + lane], v, o1);
        }
        m0 = fmaxf(m0, o0);
        m1 = fmaxf(m1, o1);
    }
    out[(size_t)qid * 128 + lane] = m0;
    out[(size_t)qid * 128 + 64 + lane] = m1;
}

// ---------- SA2 conv: one wave per query; feat=[x1(128), rel(6)] -> 128 -> 128 -> 256 ----------

__global__ __launch_bounds__(256) void sa2_conv(const float* __restrict__ pos1, const float* __restrict__ posq,
                                                const int* __restrict__ nbr, const int* __restrict__ cnt,
                                                const float* __restrict__ x1,
                                                const float* __restrict__ W1, const float* __restrict__ B1,
                                                const float* __restrict__ W2, const float* __restrict__ B2,
                                                const float* __restrict__ W3, const float* __restrict__ B3,
                                                float* __restrict__ out) {
    int lane = threadIdx.x & 63;
    int w = threadIdx.x >> 6;
    int qid = blockIdx.x * 4 + w;
    int b = qid / NS2_;
    float q[6];
#pragma unroll
    for (int d = 0; d < 6; ++d) q[d] = posq[(size_t)qid * 6 + d];
    int c = cnt[qid];
    float m0 = -INFINITY, m1 = -INFINITY, m2 = -INFINITY, m3 = -INFINITY;

    for (int n = 0; n < c; ++n) {
        int j = nbr[(size_t)qid * K_ + n];
        size_t row = (size_t)b * NS1_ + j;
        const float* xs = x1 + row * 128;
        float rel[6];
#pragma unroll
        for (int d = 0; d < 6; ++d) rel[d] = pos1[row * 6 + d] - q[d];
        float a0 = B1[lane], a1 = B1[64 + lane];
        for (int k = 0; k < 128; ++k) {
            float v = xs[k];
            a0 = fmaf(W1[k * 128 + lane], v, a0);
            a1 = fmaf(W1[k * 128 + 64 + lane], v, a1);
        }
#pragma unroll
        for (int d = 0; d < 6; ++d) {
            float v = rel[d];
            a0 = fmaf(W1[(128 + d) * 128 + lane], v, a0);
            a1 = fmaf(W1[(128 + d) * 128 + 64 + lane], v, a1);
        }
        float h1a = fmaxf(a0, 0.f), h1b = fmaxf(a1, 0.f);
        float c0 = B2[lane], c1 = B2[64 + lane];
        for (int k = 0; k < 64; ++k) {
            float v = __shfl(h1a, k, 64);
            c0 = fmaf(W2[k * 128 + lane], v, c0);
            c1 = fmaf(W2[k * 128 + 64 + lane], v, c1);
        }
        for (int k = 0; k < 64; ++k) {
            float v = __shfl(h1b, k, 64);
            c0 = fmaf(W2[(64 + k) * 128 + lane], v, c0);
            c1 = fmaf(W2[(64 + k) * 128 + 64 + lane], v, c1);
        }
        float h2a = fmaxf(c0, 0.f), h2b = fmaxf(c1, 0.f);
        float e0 = B3[lane], e1 = B3[64 + lane], e2 = B3[128 + lane], e3 = B3[192 + lane];
        for (int k = 0; k < 64; ++k) {
            float v = __shfl(h2a, k, 64);
            e0 = fmaf(W3[k * 256 + lane], v, e0);
            e1 = fmaf(W3[k * 256 + 64 + lane], v, e1);
            e2 = fmaf(W3[k * 256 + 128 + lane], v, e2);
            e3 = fmaf(W3[k * 256 + 192 + lane], v, e3);
        }
        for (int k = 0; k < 64; ++k) {
            float v = __shfl(h2b, k, 64);
            e0 = fmaf(W3[(64 + k) * 256 + lane], v, e0);
            e1 = fmaf(W3[(64 + k) * 256 + 64 + lane], v, e1);
            e2 = fmaf(W3[(64 + k) * 256 + 128 + lane], v, e2);
            e3 = fmaf(W3[(64 + k) * 256 + 192 + lane], v, e3);
        }
        m0 = fmaxf(m0, e0);
        m1 = fmaxf(m1, e1);
        m2 = fmaxf(m2, e2);
        m3 = fmaxf(m3, e3);
    }
    out[(size_t)qid * 256 + lane] = m0;
    out[(size_t)qid * 256 + 64 + lane] = m1;
    out[(size_t)qid * 256 + 128 + lane] = m2;
    out[(size_t)qid * 256 + 192 + lane] = m3;
}

// ---------- MLP3 v2: wave = 4 queries register-blocked; weight float4 reused across queries ----------

__global__ __launch_bounds__(256, 1) void mlp3_kernel(const float* __restrict__ x2, const float* __restrict__ pos2,
                                                      const float* __restrict__ W0, const float* __restrict__ B0,
                                                      const float* __restrict__ W1, const float* __restrict__ B1,
                                                      const float* __restrict__ W2, const float* __restrict__ B2,
                                                      unsigned* __restrict__ g) {
    int lane = threadIdx.x & 63;
    int w = threadIdx.x >> 6;
    int qid0 = blockIdx.x * 16 + w * 4;  // 4 queries per wave, 16 per block
    int b = qid0 >> 9;                   // 512 queries per cloud

    float xr[4][4];
#pragma unroll
    for (int q = 0; q < 4; ++q)
#pragma unroll
        for (int j = 0; j < 4; ++j) xr[q][j] = x2[(size_t)(qid0 + q) * 256 + j * 64 + lane];

    // ---- L1: 262 -> 256, out channel = lane*4+u ----
    float a[4][4];
    {
        float4 bv = *(const float4*)&B0[lane * 4];
#pragma unroll
        for (int q = 0; q < 4; ++q) { a[q][0] = bv.x; a[q][1] = bv.y; a[q][2] = bv.z; a[q][3] = bv.w; }
    }
#pragma unroll
    for (int j = 0; j < 4; ++j) {
        for (int k2 = 0; k2 < 64; ++k2) {
            int k = j * 64 + k2;
            float4 wv = *(const float4*)&W0[(size_t)k * 256 + lane * 4];
#pragma unroll
            for (int q = 0; q < 4; ++q) {
                float v = __shfl(xr[q][j], k2, 64);
                a[q][0] = fmaf(wv.x, v, a[q][0]);
                a[q][1] = fmaf(wv.y, v, a[q][1]);
                a[q][2] = fmaf(wv.z, v, a[q][2]);
                a[q][3] = fmaf(wv.w, v, a[q][3]);
            }
        }
    }
#pragma unroll
    for (int d = 0; d < 6; ++d) {
        float4 wv = *(const float4*)&W0[(size_t)(256 + d) * 256 + lane * 4];
#pragma unroll
        for (int q = 0; q < 4; ++q) {
            float v = pos2[(size_t)(qid0 + q) * 6 + d];
            a[q][0] = fmaf(wv.x, v, a[q][0]);
            a[q][1] = fmaf(wv.y, v, a[q][1]);
            a[q][2] = fmaf(wv.z, v, a[q][2]);
            a[q][3] = fmaf(wv.w, v, a[q][3]);
        }
    }
    float h1[4][4];
#pragma unroll
    for (int q = 0; q < 4; ++q)
#pragma unroll
        for (int u = 0; u < 4; ++u) h1[q][u] = fmaxf(a[q][u], 0.f);

    // ---- L2: 256 -> 512, out channel = lane*8+u ----
    float c[4][8];
    {
        float4 b0 = *(const float4*)&B1[lane * 8];
        float4 b1 = *(const float4*)&B1[lane * 8 + 4];
#pragma unroll
        for (int q = 0; q < 4; ++q) {
            c[q][0] = b0.x; c[q][1] = b0.y; c[q][2] = b0.z; c[q][3] = b0.w;
            c[q][4] = b1.x; c[q][5] = b1.y; c[q][6] = b1.z; c[q][7] = b1.w;
        }
    }
    for (int l = 0; l < 64; ++l) {
#pragma unroll
        for (int r = 0; r < 4; ++r) {
            int k = l * 4 + r;
            float4 w0 = *(const float4*)&W1[(size_t)k * 512 + lane * 8];
            float4 w1 = *(const float4*)&W1[(size_t)k * 512 + lane * 8 + 4];
#pragma unroll
            for (int q = 0; q < 4; ++q) {
                float v = __shfl(h1[q][r], l, 64);
                c[q][0] = fmaf(w0.x, v, c[q][0]);
                c[q][1] = fmaf(w0.y, v, c[q][1]);
                c[q][2] = fmaf(w0.z, v, c[q][2]);
                c[q][3] = fmaf(w0.w, v, c[q][3]);
                c[q][4] = fmaf(w1.x, v, c[q][4]);
                c[q][5] = fmaf(w1.y, v, c[q][5]);
                c[q][6] = fmaf(w1.z, v, c[q][6]);
                c[q][7] = fmaf(w1.w, v, c[q][7]);
            }
        }
    }
    float h2[4][8];
#pragma unroll
    for (int q = 0; q < 4; ++q)
#pragma unroll
        for (int u = 0; u < 8; ++u) h2[q][u] = fmaxf(c[q][u], 0.f);

    // ---- L3: 512 -> 1024, out channel = lane*16+u ----
    float e[4][16];
#pragma unroll
    for (int jj = 0; jj < 4; ++jj) {
        float4 bv = *(const float4*)&B2[lane * 16 + jj * 4];
#pragma unroll
        for (int q = 0; q < 4; ++q) {
            e[q][jj * 4 + 0] = bv.x; e[q][jj * 4 + 1] = bv.y;
            e[q][jj * 4 + 2] = bv.z; e[q][jj * 4 + 3] = bv.w;
        }
    }
    for (int l = 0; l < 64; ++l) {
#pragma unroll
        for (int r = 0; r < 8; ++r) {
            int k = l * 8 + r;
            const float* wp = &W2[(size_t)k * 1024 + lane * 16];
            float4 w0 = *(const float4*)&wp[0];
            float4 w1 = *(const float4*)&wp[4];
            float4 w2 = *(const float4*)&wp[8];
            float4 w3 = *(const float4*)&wp[12];
#pragma unroll
            for (int q = 0; q < 4; ++q) {
                float v = __shfl(h2[q][r], l, 64);
                e[q][0]  = fmaf(w0.x, v, e[q][0]);
                e[q][1]  = fmaf(w0.y, v, e[q][1]);
                e[q][2]  = fmaf(w0.z, v, e[q][2]);
                e[q][3]  = fmaf(w0.w, v, e[q][3]);
                e[q][4]  = fmaf(w1.x, v, e[q][4]);
                e[q][5]  = fmaf(w1.y, v, e[q][5]);
                e[q][6]  = fmaf(w1.z, v, e[q][6]);
                e[q][7]  = fmaf(w1.w, v, e[q][7]);
                e[q][8]  = fmaf(w2.x, v, e[q][8]);
                e[q][9]  = fmaf(w2.y, v, e[q][9]);
                e[q][10] = fmaf(w2.z, v, e[q][10]);
                e[q][11] = fmaf(w2.w, v, e[q][11]);
                e[q][12] = fmaf(w3.x, v, e[q][12]);
                e[q][13] = fmaf(w3.y, v, e[q][13]);
                e[q][14] = fmaf(w3.z, v, e[q][14]);
                e[q][15] = fmaf(w3.w, v, e[q][15]);
            }
        }
    }
#pragma unroll
    for (int u = 0; u < 16; ++u) {
        float m = fmaxf(fmaxf(e[0][u], e[1][u]), fmaxf(e[2][u], e[3][u]));
        atomicMax(&g[b * 1024 + lane * 16 + u], mapf(m));
    }
}

// ---------- MLP4: 1024 -> 512 (relu) -> 512; one block per b ----------

__global__ __launch_bounds__(512) void mlp4_kernel(const unsigned* __restrict__ g,
                                                   const float* __restrict__ W0, const float* __restrict__ B0,
                                                   const float* __restrict__ W1, const float* __restrict__ B1,
                                                   float* __restrict__ out) {
    int b = blockIdx.x;
    int c = threadIdx.x;
    __shared__ float h[512];
    float a = B0[c];
    for (int k = 0; k < 1024; ++k) {
        float v = unmapf(g[b * 1024 + k]);
        a = fmaf(v, W0[k * 512 + c], a);
    }
    h[c] = fmaxf(a, 0.f);
    __syncthreads();
    float o = B1[c];
    for (int k = 0; k < 512; ++k) o = fmaf(h[k], W1[k * 512 + c], o);
    out[(size_t)b * 512 + c] = o;
}

// ---------- launch ----------

extern "C" void kernel_launch(void* const* d_in, const int* in_sizes, int n_in,
                              void* d_out, int out_size, void* d_ws, size_t ws_size,
                              hipStream_t stream) {
    const float* pos = (const float*)d_in[0];  // [B*N, 6]
    const float* w1_0 = (const float*)d_in[3];
    const float* b1_0 = (const float*)d_in[4];
    const float* w1_1 = (const float*)d_in[5];
    const float* b1_1 = (const float*)d_in[6];
    const float* w1_2 = (const float*)d_in[7];
    const float* b1_2 = (const float*)d_in[8];
    const float* w2_0 = (const float*)d_in[9];
    const float* b2_0 = (const float*)d_in[10];
    const float* w2_1 = (const float*)d_in[11];
    const float* b2_1 = (const float*)d_in[12];
    const float* w2_2 = (const float*)d_in[13];
    const float* b2_2 = (const float*)d_in[14];
    const float* w3_0 = (const float*)d_in[15];
    const float* b3_0 = (const float*)d_in[16];
    const float* w3_1 = (const float*)d_in[17];
    const float* b3_1 = (const float*)d_in[18];
    const float* w3_2 = (const float*)d_in[19];
    const float* b3_2 = (const float*)d_in[20];
    const float* w4_0 = (const float*)d_in[21];
    const float* b4_0 = (const float*)d_in[22];
    const float* w4_1 = (const float*)d_in[23];
    const float* b4_1 = (const float*)d_in[24];
    float* out = (float*)d_out;

    char* ws = (char*)d_ws;
    size_t off = 0;
    float* pos1 = (float*)(ws + off);  off += (size_t)B_ * NS1_ * 6 * 4;
    int* nbr1 = (int*)(ws + off);      off += (size_t)B_ * NS1_ * K_ * 4;
    int* cnt1 = (int*)(ws + off);      off += (size_t)B_ * NS1_ * 4;
    float* x1 = (float*)(ws + off);    off += (size_t)B_ * NS1_ * 128 * 4;
    float* pos2 = (float*)(ws + off);  off += (size_t)B_ * NS2_ * 6 * 4;
    int* nbr2 = (int*)(ws + off);      off += (size_t)B_ * NS2_ * K_ * 4;
    int* cnt2 = (int*)(ws + off);      off += (size_t)B_ * NS2_ * 4;
    float* x2 = (float*)(ws + off);    off += (size_t)B_ * NS2_ * 256 * 4;
    unsigned* g = (unsigned*)(ws + off); off += (size_t)B_ * 1024 * 4;

    const float r2_1 = (float)(0.2 * 0.2);
    const float r2_2 = (float)(0.4 * 0.4);

    // SA1
    fps_kernel<N_, NS1_, false><<<B_, 256, 0, stream>>>(pos, pos1, nullptr);
    ball_kernel<<<(B_ * NS1_) / 64, 64, 0, stream>>>(pos, pos1, nbr1, cnt1, N_, NS1_, r2_1);
    sa1_conv<<<(B_ * NS1_) / 4, 256, 0, stream>>>(pos, pos1, nbr1, cnt1,
                                                  w1_0, b1_0, w1_1, b1_1, w1_2, b1_2, x1, N_, NS1_);
    // SA2 (fps2 also zeroes g for mlp3)
    fps_kernel<NS1_, NS2_, true><<<B_, 256, 0, stream>>>(pos1, pos2, g);
    ball_kernel<<<(B_ * NS2_) / 64, 64, 0, stream>>>(pos1, pos2, nbr2, cnt2, NS1_, NS2_, r2_2);
    sa2_conv<<<(B_ * NS2_) / 4, 256, 0, stream>>>(pos1, pos2, nbr2, cnt2, x1,
                                                  w2_0, b2_0, w2_1, b2_1, w2_2, b2_2, x2);
    // MLP3 + global max
    mlp3_kernel<<<(B_ * NS2_) / 16, 256, 0, stream>>>(x2, pos2, w3_0, b3_0, w3_1, b3_1, w3_2, b3_2, g);
    // MLP4
    mlp4_kernel<<<B_, 512, 0, stream>>>(g, w4_0, b4_0, w4_1, b4_1, out);
}

// Round 10
// 2876.840 us; speedup vs baseline: 1.2353x; 1.0963x over previous
//
#include <hip/hip_runtime.h>
#include <math.h>

#define B_ 8
#define N_ 4096
#define D_ 6
#define K_ 64
#define NS1_ 2048
#define NS2_ 512

typedef float v2f __attribute__((ext_vector_type(2)));

// ---------- helpers ----------

__device__ __forceinline__ float dist2_rn(const float* __restrict__ a, const float* __restrict__ q) {
    // exact np semantics: sequential sum of (a-b)^2, round-to-nearest each op, no fma
    float s = 0.f;
#pragma unroll
    for (int d = 0; d < 6; ++d) {
        float diff = __fsub_rn(a[d], q[d]);
        s = __fadd_rn(s, __fmul_rn(diff, diff));
    }
    return s;
}

__device__ __forceinline__ unsigned mapf(float x) {
    unsigned u = __float_as_uint(x);
    return (u & 0x80000000u) ? ~u : (u | 0x80000000u);
}
__device__ __forceinline__ float unmapf(unsigned u) {
    return __uint_as_float((u & 0x80000000u) ? (u & 0x7FFFFFFFu) : ~u);
}

// DPP move on a f64 key (two 32-bit DPPs); invalid lanes keep own value (identity for max).
// Keys are non-negative doubles bitwise == (d2_fp32_bits<<32 | ~idx): u64 order == f64 order.
template <int CTRL>
__device__ __forceinline__ double dppd(double k) {
    int lo = __double2loint(k), hi = __double2hiint(k);
    int nlo = __builtin_amdgcn_update_dpp(lo, lo, CTRL, 0xF, 0xF, false);
    int nhi = __builtin_amdgcn_update_dpp(hi, hi, CTRL, 0xF, 0xF, false);
    return __hiloint2double(nhi, nlo);
}

// ---------- FPS body (v9, proven): f64-fmax DPP ladder + vector update ----------
// p, posq, g pre-offset to this cloud. Exact np semantics: contract(off) rn chain, fminf,
// strict-> first-occurrence argmax (key hi=d2 bits, lo=~gidx).

template <int NP, int NS, bool ZG>
__device__ __forceinline__ void fps_body(const float* __restrict__ p, float* __restrict__ posq,
                                         unsigned* __restrict__ g, float* __restrict__ spos,
                                         int* __restrict__ sidx, double* __restrict__ part, int t) {
#pragma clang fp contract(off)
    constexpr int NT = 256;
    constexpr int P = NP / NT;
    constexpr int HP = P / 2;
    int lane = t & 63, w = t >> 6;

    // stage into LDS, coalesced float4
    {
        const float4* src = (const float4*)p;
        float4* dst = (float4*)spos;
        for (int e = t; e < NP * 6 / 4; e += NT) dst[e] = src[e];
    }
    if (t == 0) sidx[0] = 0;
    __syncthreads();

    // this thread's points in vector pairs: pair j = points t+NT*(2j), t+NT*(2j+1)
    v2f px2[HP][6];
#pragma unroll
    for (int j = 0; j < HP; ++j)
#pragma unroll
        for (int d = 0; d < 6; ++d) {
            px2[j][d].x = spos[(t + NT * (2 * j)) * 6 + d];
            px2[j][d].y = spos[(t + NT * (2 * j + 1)) * 6 + d];
        }

    // first sample = point 0
    float cx[6];
#pragma unroll
    for (int d = 0; d < 6; ++d) cx[d] = spos[d];

    v2f mind2[HP];
    float runv = -1.f;
    int runj = 0;
#pragma unroll
    for (int j = 0; j < HP; ++j) {
        v2f d2 = {0.f, 0.f};
#pragma unroll
        for (int d = 0; d < 6; ++d) {
            v2f df = px2[j][d] - cx[d];
            d2 = d2 + df * df;
        }
        mind2[j] = d2;
        if (d2.x > runv) { runv = d2.x; runj = t + NT * (2 * j); }      // ascending gidx:
        if (d2.y > runv) { runv = d2.y; runj = t + NT * (2 * j + 1); }  // strict > keeps lowest
    }

    for (int s = 1; s < NS; ++s) {
        // wave-level argmax reduce via f64-fmax DPP ladder on packed key
        double key = __hiloint2double((int)__float_as_uint(runv), (int)(unsigned)(~runj));
        key = fmax(key, dppd<0x111>(key));  // row_shr:1
        key = fmax(key, dppd<0x112>(key));  // row_shr:2
        key = fmax(key, dppd<0x114>(key));  // row_shr:4
        key = fmax(key, dppd<0x118>(key));  // row_shr:8
        key = fmax(key, dppd<0x142>(key));  // row_bcast:15
        key = fmax(key, dppd<0x143>(key));  // row_bcast:31 -> lane 63 = wave max
        if (lane == 63) part[(s & 1) * 4 + w] = key;
        __syncthreads();
        // every wave redundantly reduces the 4 partials (2 DPP levels, lanes 0..3)
        double kk = part[(s & 1) * 4 + (lane & 3)];
        kk = fmax(kk, dppd<0x111>(kk));
        kk = fmax(kk, dppd<0x112>(kk));   // lane 3 = max of partials 0..3
        int nx = ~__builtin_amdgcn_readlane(__double2loint(kk), 3);
        if (t == 0) sidx[s] = nx;  // off critical path; consumed only at the end

        // broadcast-read new center coords (nx uniform)
        const float2* sv2 = (const float2*)spos;
        float2 ca = sv2[nx * 3], cb = sv2[nx * 3 + 1], cc = sv2[nx * 3 + 2];
        cx[0] = ca.x; cx[1] = ca.y; cx[2] = cb.x; cx[3] = cb.y; cx[4] = cc.x; cx[5] = cc.y;

        // fused update (vector ops) + scalar min/argmax on components
        runv = -1.f;
        runj = 0;
#pragma unroll
        for (int j = 0; j < HP; ++j) {
            v2f d2 = {0.f, 0.f};
#pragma unroll
            for (int d = 0; d < 6; ++d) {
                v2f df = px2[j][d] - cx[d];
                d2 = d2 + df * df;
            }
            float mx = fminf(mind2[j].x, d2.x);
            float my = fminf(mind2[j].y, d2.y);
            mind2[j].x = mx;
            mind2[j].y = my;
            if (mx > runv) { runv = mx; runj = t + NT * (2 * j); }
            if (my > runv) { runv = my; runj = t + NT * (2 * j + 1); }
        }
    }
    __syncthreads();
    // write posq once, from LDS
    for (int s2 = t; s2 < NS; s2 += 256) {
        int nx = sidx[s2];
#pragma unroll
        for (int d = 0; d < 6; ++d) posq[(size_t)s2 * 6 + d] = spos[nx * 6 + d];
    }
    if (ZG) {  // zero the global-max buffer (consumed by mlp3 later)
        for (int e = t; e < 1024; e += 256) g[e] = 0u;
    }
}

// ---------- ball body (r9-proven semantics), stride-S interleaved LDS top-K ----------

template <int S, int NPTS>
__device__ __forceinline__ void ball_body(const float* __restrict__ pos, const float* __restrict__ posq,
                                          int* __restrict__ nbr, int* __restrict__ cnt,
                                          int nq, float r2, int qid, int tid,
                                          float* __restrict__ sd, int* __restrict__ si) {
    int b = qid / nq;
    const float* p = pos + (size_t)b * NPTS * 6;
    float q[6];
#pragma unroll
    for (int d = 0; d < 6; ++d) q[d] = posq[(size_t)qid * 6 + d];

    int n = 0;
    float thr = INFINITY;
#pragma unroll 4
    for (int j = 0; j < NPTS; ++j) {
        float d2 = dist2_rn(p + (size_t)j * 6, q);
        if (d2 <= r2 && (n < K_ || d2 < thr)) {
            int i = (n < K_) ? n : (K_ - 1);
            if (n < K_) ++n;
            while (i > 0 && sd[(i - 1) * S + tid] > d2) {
                sd[i * S + tid] = sd[(i - 1) * S + tid];
                si[i * S + tid] = si[(i - 1) * S + tid];
                --i;
            }
            sd[i * S + tid] = d2;
            si[i * S + tid] = j;
            if (n == K_) thr = sd[(K_ - 1) * S + tid];
        }
    }
    cnt[qid] = n;
    for (int i = 0; i < n; ++i) nbr[(size_t)qid * K_ + i] = si[i * S + tid];
}

// ---------- fps1 standalone ----------

template <int NP, int NS>
__global__ __launch_bounds__(256, 1) void fps_kernel(const float* __restrict__ pos,
                                                     float* __restrict__ posq) {
    __shared__ float spos[NP * 6];
    __shared__ int sidx[NS];
    __shared__ double part[8];
    int b = blockIdx.x;
    fps_body<NP, NS, false>(pos + (size_t)b * NP * 6, posq + (size_t)b * NS * 6, nullptr,
                            spos, sidx, part, threadIdx.x);
}

// ---------- merged kernel A: blocks 0..63 = ball1 (256 queries/block), 64..71 = fps2 (+zero g) ----------

__global__ __launch_bounds__(256, 1) void ball1_fps2_kernel(const float* __restrict__ pos,
                                                            const float* __restrict__ pos1,
                                                            int* __restrict__ nbr1, int* __restrict__ cnt1,
                                                            float* __restrict__ pos2,
                                                            unsigned* __restrict__ g, float r2) {
    __shared__ union SmemA {
        struct { float sd[K_ * 256]; int si[K_ * 256]; } ball;                 // 128 KB
        struct { float spos[NS1_ * 6]; int sidx[NS2_]; double part[8]; } fps;  // ~50 KB
    } sm;
    if (blockIdx.x < 64) {
        int qid = blockIdx.x * 256 + threadIdx.x;
        ball_body<256, N_>(pos, pos1, nbr1, cnt1, NS1_, r2, qid, threadIdx.x,
                           sm.ball.sd, sm.ball.si);
    } else {
        int b = blockIdx.x - 64;
        fps_body<NS1_, NS2_, true>(pos1 + (size_t)b * NS1_ * 6, pos2 + (size_t)b * NS2_ * 6,
                                   g + b * 1024, sm.fps.spos, sm.fps.sidx, sm.fps.part,
                                   threadIdx.x);
    }
}

// ---------- merged kernel B: blocks 0..4095 = sa1 (4 queries/block), 4096..4159 = ball2 ----------

__global__ __launch_bounds__(256) void sa1_ball2_kernel(const float* __restrict__ pos,
                                                        const float* __restrict__ pos1,
                                                        const int* __restrict__ nbr1,
                                                        const int* __restrict__ cnt1,
                                                        const float* __restrict__ W1, const float* __restrict__ B1,
                                                        const float* __restrict__ W2, const float* __restrict__ B2,
                                                        const float* __restrict__ W3, const float* __restrict__ B3,
                                                        float* __restrict__ x1,
                                                        const float* __restrict__ pos2,
                                                        int* __restrict__ nbr2, int* __restrict__ cnt2,
                                                        float r2_2) {
    __shared__ float sd[K_ * 64];
    __shared__ int si[K_ * 64];
    if (blockIdx.x >= 4096) {
        if (threadIdx.x >= 64) return;
        int qid = (blockIdx.x - 4096) * 64 + threadIdx.x;
        ball_body<64, NS1_>(pos1, pos2, nbr2, cnt2, NS2_, r2_2, qid, threadIdx.x, sd, si);
        return;
    }
    // ---- sa1: one wave per query; MLP 6->64->64->128, max over valid neighbors ----
    int lane = threadIdx.x & 63;
    int w = threadIdx.x >> 6;
    int qid = blockIdx.x * 4 + w;
    int b = qid / NS1_;
    const float* p = pos + (size_t)b * N_ * 6;
    float q[6];
#pragma unroll
    for (int d = 0; d < 6; ++d) q[d] = pos1[(size_t)qid * 6 + d];
    int c = cnt1[qid];
    float m0 = -INFINITY, m1 = -INFINITY;

    for (int n = 0; n < c; ++n) {
        int j = nbr1[(size_t)qid * K_ + n];
        float rel[6];
#pragma unroll
        for (int d = 0; d < 6; ++d) rel[d] = p[(size_t)j * 6 + d] - q[d];
        float a = B1[lane];
#pragma unroll
        for (int d = 0; d < 6; ++d) a = fmaf(W1[d * 64 + lane], rel[d], a);
        float h1 = fmaxf(a, 0.f);
        float a2 = B2[lane];
        for (int k = 0; k < 64; ++k) {
            float v = __shfl(h1, k, 64);
            a2 = fmaf(W2[k * 64 + lane], v, a2);
        }
        float h2 = fmaxf(a2, 0.f);
        float o0 = B3[lane], o1 = B3[64 + lane];
        for (int k = 0; k < 64; ++k) {
            float v = __shfl(h2, k, 64);
            o0 = fmaf(W3[k * 128 + lane], v, o0);
            o1 = fmaf(W3[k * 128 + 64 + lane], v, o1);
        }
        m0 = fmaxf(m0, o0);
        m1 = fmaxf(m1, o1);
    }
    x1[(size_t)qid * 128 + lane] = m0;
    x1[(size_t)qid * 128 + 64 + lane] = m1;
}

// ---------- SA2 conv: one wave per query; feat=[x1(128), rel(6)] -> 128 -> 128 -> 256 ----------

__global__ __launch_bounds__(256) void sa2_conv(const float* __restrict__ pos1, const float* __restrict__ posq,
                                                const int* __restrict__ nbr, const int* __restrict__ cnt,
                                                const float* __restrict__ x1,
                                                const float* __restrict__ W1, const float* __restrict__ B1,
                                                const float* __restrict__ W2, const float* __restrict__ B2,
                                                const float* __restrict__ W3, const float* __restrict__ B3,
                                                float* __restrict__ out) {
    int lane = threadIdx.x & 63;
    int w = threadIdx.x >> 6;
    int qid = blockIdx.x * 4 + w;
    int b = qid / NS2_;
    float q[6];
#pragma unroll
    for (int d = 0; d < 6; ++d) q[d] = posq[(size_t)qid * 6 + d];
    int c = cnt[qid];
    float m0 = -INFINITY, m1 = -INFINITY, m2 = -INFINITY, m3 = -INFINITY;

    for (int n = 0; n < c; ++n) {
        int j = nbr[(size_t)qid * K_ + n];
        size_t row = (size_t)b * NS1_ + j;
        const float* xs = x1 + row * 128;
        float rel[6];
#pragma unroll
        for (int d = 0; d < 6; ++d) rel[d] = pos1[row * 6 + d] - q[d];
        float a0 = B1[lane], a1 = B1[64 + lane];
        for (int k = 0; k < 128; ++k) {
            float v = xs[k];
            a0 = fmaf(W1[k * 128 + lane], v, a0);
            a1 = fmaf(W1[k * 128 + 64 + lane], v, a1);
        }
#pragma unroll
        for (int d = 0; d < 6; ++d) {
            float v = rel[d];
            a0 = fmaf(W1[(128 + d) * 128 + lane], v, a0);
            a1 = fmaf(W1[(128 + d) * 128 + 64 + lane], v, a1);
        }
        float h1a = fmaxf(a0, 0.f), h1b = fmaxf(a1, 0.f);
        float c0 = B2[lane], c1 = B2[64 + lane];
        for (int k = 0; k < 64; ++k) {
            float v = __shfl(h1a, k, 64);
            c0 = fmaf(W2[k * 128 + lane], v, c0);
            c1 = fmaf(W2[k * 128 + 64 + lane], v, c1);
        }
        for (int k = 0; k < 64; ++k) {
            float v = __shfl(h1b, k, 64);
            c0 = fmaf(W2[(64 + k) * 128 + lane], v, c0);
            c1 = fmaf(W2[(64 + k) * 128 + 64 + lane], v, c1);
        }
        float h2a = fmaxf(c0, 0.f), h2b = fmaxf(c1, 0.f);
        float e0 = B3[lane], e1 = B3[64 + lane], e2 = B3[128 + lane], e3 = B3[192 + lane];
        for (int k = 0; k < 64; ++k) {
            float v = __shfl(h2a, k, 64);
            e0 = fmaf(W3[k * 256 + lane], v, e0);
            e1 = fmaf(W3[k * 256 + 64 + lane], v, e1);
            e2 = fmaf(W3[k * 256 + 128 + lane], v, e2);
            e3 = fmaf(W3[k * 256 + 192 + lane], v, e3);
        }
        for (int k = 0; k < 64; ++k) {
            float v = __shfl(h2b, k, 64);
            e0 = fmaf(W3[(64 + k) * 256 + lane], v, e0);
            e1 = fmaf(W3[(64 + k) * 256 + 64 + lane], v, e1);
            e2 = fmaf(W3[(64 + k) * 256 + 128 + lane], v, e2);
            e3 = fmaf(W3[(64 + k) * 256 + 192 + lane], v, e3);
        }
        m0 = fmaxf(m0, e0);
        m1 = fmaxf(m1, e1);
        m2 = fmaxf(m2, e2);
        m3 = fmaxf(m3, e3);
    }
    out[(size_t)qid * 256 + lane] = m0;
    out[(size_t)qid * 256 + 64 + lane] = m1;
    out[(size_t)qid * 256 + 128 + lane] = m2;
    out[(size_t)qid * 256 + 192 + lane] = m3;
}

// ---------- MLP3 v2: wave = 4 queries register-blocked; weight float4 reused across queries ----------

__global__ __launch_bounds__(256, 1) void mlp3_kernel(const float* __restrict__ x2, const float* __restrict__ pos2,
                                                      const float* __restrict__ W0, const float* __restrict__ B0,
                                                      const float* __restrict__ W1, const float* __restrict__ B1,
                                                      const float* __restrict__ W2, const float* __restrict__ B2,
                                                      unsigned* __restrict__ g) {
    int lane = threadIdx.x & 63;
    int w = threadIdx.x >> 6;
    int qid0 = blockIdx.x * 16 + w * 4;  // 4 queries per wave, 16 per block
    int b = qid0 >> 9;                   // 512 queries per cloud

    float xr[4][4];
#pragma unroll
    for (int q = 0; q < 4; ++q)
#pragma unroll
        for (int j = 0; j < 4; ++j) xr[q][j] = x2[(size_t)(qid0 + q) * 256 + j * 64 + lane];

    // ---- L1: 262 -> 256, out channel = lane*4+u ----
    float a[4][4];
    {
        float4 bv = *(const float4*)&B0[lane * 4];
#pragma unroll
        for (int q = 0; q < 4; ++q) { a[q][0] = bv.x; a[q][1] = bv.y; a[q][2] = bv.z; a[q][3] = bv.w; }
    }
#pragma unroll
    for (int j = 0; j < 4; ++j) {
        for (int k2 = 0; k2 < 64; ++k2) {
            int k = j * 64 + k2;
            float4 wv = *(const float4*)&W0[(size_t)k * 256 + lane * 4];
#pragma unroll
            for (int q = 0; q < 4; ++q) {
                float v = __shfl(xr[q][j], k2, 64);
                a[q][0] = fmaf(wv.x, v, a[q][0]);
                a[q][1] = fmaf(wv.y, v, a[q][1]);
                a[q][2] = fmaf(wv.z, v, a[q][2]);
                a[q][3] = fmaf(wv.w, v, a[q][3]);
            }
        }
    }
#pragma unroll
    for (int d = 0; d < 6; ++d) {
        float4 wv = *(const float4*)&W0[(size_t)(256 + d) * 256 + lane * 4];
#pragma unroll
        for (int q = 0; q < 4; ++q) {
            float v = pos2[(size_t)(qid0 + q) * 6 + d];
            a[q][0] = fmaf(wv.x, v, a[q][0]);
            a[q][1] = fmaf(wv.y, v, a[q][1]);
            a[q][2] = fmaf(wv.z, v, a[q][2]);
            a[q][3] = fmaf(wv.w, v, a[q][3]);
        }
    }
    float h1[4][4];
#pragma unroll
    for (int q = 0; q < 4; ++q)
#pragma unroll
        for (int u = 0; u < 4; ++u) h1[q][u] = fmaxf(a[q][u], 0.f);

    // ---- L2: 256 -> 512, out channel = lane*8+u ----
    float c[4][8];
    {
        float4 b0 = *(const float4*)&B1[lane * 8];
        float4 b1 = *(const float4*)&B1[lane * 8 + 4];
#pragma unroll
        for (int q = 0; q < 4; ++q) {
            c[q][0] = b0.x; c[q][1] = b0.y; c[q][2] = b0.z; c[q][3] = b0.w;
            c[q][4] = b1.x; c[q][5] = b1.y; c[q][6] = b1.z; c[q][7] = b1.w;
        }
    }
    for (int l = 0; l < 64; ++l) {
#pragma unroll
        for (int r = 0; r < 4; ++r) {
            int k = l * 4 + r;
            float4 w0 = *(const float4*)&W1[(size_t)k * 512 + lane * 8];
            float4 w1 = *(const float4*)&W1[(size_t)k * 512 + lane * 8 + 4];
#pragma unroll
            for (int q = 0; q < 4; ++q) {
                float v = __shfl(h1[q][r], l, 64);
                c[q][0] = fmaf(w0.x, v, c[q][0]);
                c[q][1] = fmaf(w0.y, v, c[q][1]);
                c[q][2] = fmaf(w0.z, v, c[q][2]);
                c[q][3] = fmaf(w0.w, v, c[q][3]);
                c[q][4] = fmaf(w1.x, v, c[q][4]);
                c[q][5] = fmaf(w1.y, v, c[q][5]);
                c[q][6] = fmaf(w1.z, v, c[q][6]);
                c[q][7] = fmaf(w1.w, v, c[q][7]);
            }
        }
    }
    float h2[4][8];
#pragma unroll
    for (int q = 0; q < 4; ++q)
#pragma unroll
        for (int u = 0; u < 8; ++u) h2[q][u] = fmaxf(c[q][u], 0.f);

    // ---- L3: 512 -> 1024, out channel = lane*16+u ----
    float e[4][16];
#pragma unroll
    for (int jj = 0; jj < 4; ++jj) {
        float4 bv = *(const float4*)&B2[lane * 16 + jj * 4];
#pragma unroll
        for (int q = 0; q < 4; ++q) {
            e[q][jj * 4 + 0] = bv.x; e[q][jj * 4 + 1] = bv.y;
            e[q][jj * 4 + 2] = bv.z; e[q][jj * 4 + 3] = bv.w;
        }
    }
    for (int l = 0; l < 64; ++l) {
#pragma unroll
        for (int r = 0; r < 8; ++r) {
            int k = l * 8 + r;
            const float* wp = &W2[(size_t)k * 1024 + lane * 16];
            float4 w0 = *(const float4*)&wp[0];
            float4 w1 = *(const float4*)&wp[4];
            float4 w2 = *(const float4*)&wp[8];
            float4 w3 = *(const float4*)&wp[12];
#pragma unroll
            for (int q = 0; q < 4; ++q) {
                float v = __shfl(h2[q][r], l, 64);
                e[q][0]  = fmaf(w0.x, v, e[q][0]);
                e[q][1]  = fmaf(w0.y, v, e[q][1]);
                e[q][2]  = fmaf(w0.z, v, e[q][2]);
                e[q][3]  = fmaf(w0.w, v, e[q][3]);
                e[q][4]  = fmaf(w1.x, v, e[q][4]);
                e[q][5]  = fmaf(w1.y, v, e[q][5]);
                e[q][6]  = fmaf(w1.z, v, e[q][6]);
                e[q][7]  = fmaf(w1.w, v, e[q][7]);
                e[q][8]  = fmaf(w2.x, v, e[q][8]);
                e[q][9]  = fmaf(w2.y, v, e[q][9]);
                e[q][10] = fmaf(w2.z, v, e[q][10]);
                e[q][11] = fmaf(w2.w, v, e[q][11]);
                e[q][12] = fmaf(w3.x, v, e[q][12]);
                e[q][13] = fmaf(w3.y, v, e[q][13]);
                e[q][14] = fmaf(w3.z, v, e[q][14]);
                e[q][15] = fmaf(w3.w, v, e[q][15]);
            }
        }
    }
#pragma unroll
    for (int u = 0; u < 16; ++u) {
        float m = fmaxf(fmaxf(e[0][u], e[1][u]), fmaxf(e[2][u], e[3][u]));
        atomicMax(&g[b * 1024 + lane * 16 + u], mapf(m));
    }
}

// ---------- MLP4: 1024 -> 512 (relu) -> 512; one block per b ----------

__global__ __launch_bounds__(512) void mlp4_kernel(const unsigned* __restrict__ g,
                                                   const float* __restrict__ W0, const float* __restrict__ B0,
                                                   const float* __restrict__ W1, const float* __restrict__ B1,
                                                   float* __restrict__ out) {
    int b = blockIdx.x;
    int c = threadIdx.x;
    __shared__ float h[512];
    float a = B0[c];
    for (int k = 0; k < 1024; ++k) {
        float v = unmapf(g[b * 1024 + k]);
        a = fmaf(v, W0[k * 512 + c], a);
    }
    h[c] = fmaxf(a, 0.f);
    __syncthreads();
    float o = B1[c];
    for (int k = 0; k < 512; ++k) o = fmaf(h[k], W1[k * 512 + c], o);
    out[(size_t)b * 512 + c] = o;
}

// ---------- launch ----------

extern "C" void kernel_launch(void* const* d_in, const int* in_sizes, int n_in,
                              void* d_out, int out_size, void* d_ws, size_t ws_size,
                              hipStream_t stream) {
    const float* pos = (const float*)d_in[0];  // [B*N, 6]
    const float* w1_0 = (const float*)d_in[3];
    const float* b1_0 = (const float*)d_in[4];
    const float* w1_1 = (const float*)d_in[5];
    const float* b1_1 = (const float*)d_in[6];
    const float* w1_2 = (const float*)d_in[7];
    const float* b1_2 = (const float*)d_in[8];
    const float* w2_0 = (const float*)d_in[9];
    const float* b2_0 = (const float*)d_in[10];
    const float* w2_1 = (const float*)d_in[11];
    const float* b2_1 = (const float*)d_in[12];
    const float* w2_2 = (const float*)d_in[13];
    const float* b2_2 = (const float*)d_in[14];
    const float* w3_0 = (const float*)d_in[15];
    const float* b3_0 = (const float*)d_in[16];
    const float* w3_1 = (const float*)d_in[17];
    const float* b3_1 = (const float*)d_in[18];
    const float* w3_2 = (const float*)d_in[19];
    const float* b3_2 = (const float*)d_in[20];
    const float* w4_0 = (const float*)d_in[21];
    const float* b4_0 = (const float*)d_in[22];
    const float* w4_1 = (const float*)d_in[23];
    const float* b4_1 = (const float*)d_in[24];
    float* out = (float*)d_out;

    char* ws = (char*)d_ws;
    size_t off = 0;
    float* pos1 = (float*)(ws + off);  off += (size_t)B_ * NS1_ * 6 * 4;
    int* nbr1 = (int*)(ws + off);      off += (size_t)B_ * NS1_ * K_ * 4;
    int* cnt1 = (int*)(ws + off);      off += (size_t)B_ * NS1_ * 4;
    float* x1 = (float*)(ws + off);    off += (size_t)B_ * NS1_ * 128 * 4;
    float* pos2 = (float*)(ws + off);  off += (size_t)B_ * NS2_ * 6 * 4;
    int* nbr2 = (int*)(ws + off);      off += (size_t)B_ * NS2_ * K_ * 4;
    int* cnt2 = (int*)(ws + off);      off += (size_t)B_ * NS2_ * 4;
    float* x2 = (float*)(ws + off);    off += (size_t)B_ * NS2_ * 256 * 4;
    unsigned* g = (unsigned*)(ws + off); off += (size_t)B_ * 1024 * 4;

    const float r2_1 = (float)(0.2 * 0.2);
    const float r2_2 = (float)(0.4 * 0.4);

    // 1. fps1
    fps_kernel<N_, NS1_><<<B_, 256, 0, stream>>>(pos, pos1);
    // 2. ball1 (blocks 0..63) || fps2+zero-g (blocks 64..71)
    ball1_fps2_kernel<<<72, 256, 0, stream>>>(pos, pos1, nbr1, cnt1, pos2, g, r2_1);
    // 3. sa1 (blocks 0..4095) || ball2 (blocks 4096..4159)
    sa1_ball2_kernel<<<4096 + 64, 256, 0, stream>>>(pos, pos1, nbr1, cnt1,
                                                    w1_0, b1_0, w1_1, b1_1, w1_2, b1_2, x1,
                                                    pos2, nbr2, cnt2, r2_2);
    // 4. sa2
    sa2_conv<<<(B_ * NS2_) / 4, 256, 0, stream>>>(pos1, pos2, nbr2, cnt2, x1,
                                                  w2_0, b2_0, w2_1, b2_1, w2_2, b2_2, x2);
    // 5. mlp3 + global max
    mlp3_kernel<<<(B_ * NS2_) / 16, 256, 0, stream>>>(x2, pos2, w3_0, b3_0, w3_1, b3_1, w3_2, b3_2, g);
    // 6. mlp4
    mlp4_kernel<<<B_, 512, 0, stream>>>(g, w4_0, b4_0, w4_1, b4_1, out);
}